// Round 1
// baseline (729.807 us; speedup 1.0000x reference)
//
#include <hip/hip_runtime.h>
#include <math.h>

#define TPB 256

// ---------------- CSR build ----------------
__global__ void k_hist(const int* __restrict__ dst, int* __restrict__ deg, int E) {
  int e = blockIdx.x * TPB + threadIdx.x;
  if (e < E) atomicAdd(&deg[dst[e]], 1);
}

// 1024 items/block, 256 threads, 4 items/thread
__global__ void k_scan_block(const int* __restrict__ deg, int* __restrict__ offs,
                             int* __restrict__ bsums, int n) {
  __shared__ int lds[256];
  int t = threadIdx.x, b = blockIdx.x;
  int base = b * 1024 + t * 4;
  int v0 = (base + 0 < n) ? deg[base + 0] : 0;
  int v1 = (base + 1 < n) ? deg[base + 1] : 0;
  int v2 = (base + 2 < n) ? deg[base + 2] : 0;
  int v3 = (base + 3 < n) ? deg[base + 3] : 0;
  int s = v0 + v1 + v2 + v3;
  lds[t] = s;
  __syncthreads();
  int acc = s;
  for (int off = 1; off < 256; off <<= 1) {
    int x = (t >= off) ? lds[t - off] : 0;
    __syncthreads();
    acc += x;
    lds[t] = acc;
    __syncthreads();
  }
  int excl = acc - s;
  if (base + 0 < n) offs[base + 0] = excl;
  if (base + 1 < n) offs[base + 1] = excl + v0;
  if (base + 2 < n) offs[base + 2] = excl + v0 + v1;
  if (base + 3 < n) offs[base + 3] = excl + v0 + v1 + v2;
  if (t == 255) bsums[b] = acc;
}

__global__ void k_scan_mid(int* __restrict__ bsums, int nb) {
  __shared__ int lds[128];
  int t = threadIdx.x;
  int v = (t < nb) ? bsums[t] : 0;
  lds[t] = v;
  __syncthreads();
  int acc = v;
  for (int off = 1; off < 128; off <<= 1) {
    int x = (t >= off) ? lds[t - off] : 0;
    __syncthreads();
    acc += x;
    lds[t] = acc;
    __syncthreads();
  }
  if (t < nb) bsums[t] = acc - v;  // exclusive
}

__global__ void k_scan_add(int* __restrict__ offs, const int* __restrict__ bsums,
                           int n, int total) {
  int t = threadIdx.x, b = blockIdx.x;
  int add = bsums[b];
  int base = b * 1024 + t * 4;
#pragma unroll
  for (int j = 0; j < 4; ++j)
    if (base + j < n) offs[base + j] += add;
  if (b == 0 && t == 0) offs[n] = total;
}

__global__ void k_fill(const int* __restrict__ src, const int* __restrict__ dst,
                       const float* __restrict__ attr, const int* __restrict__ offs,
                       int* __restrict__ cursor, int2* __restrict__ csr, int E) {
  int e = blockIdx.x * TPB + threadIdx.x;
  if (e < E) {
    int d = dst[e];
    int p = offs[d] + atomicAdd(&cursor[d], 1);
    csr[p] = make_int2(src[e], __float_as_int(attr[e]));
  }
}

// ---------------- Layer-1 aggregation: 16 threads/node, f<9 active ----------------
__global__ void __launch_bounds__(256) k_agg1(
    const float* __restrict__ x, const int2* __restrict__ csr,
    const int* __restrict__ offs, const float* __restrict__ We1,
    const float* __restrict__ be1, float* __restrict__ u1, int N) {
  int t = blockIdx.x * TPB + threadIdx.x;
  int node = t >> 4, f = t & 15;
  if (node >= N || f >= 9) return;
  int o0 = offs[node], o1 = offs[node + 1];
  float we = We1[f], be = be1[f];
  float acc = 0.f;
  int e = o0;
  for (; e + 1 < o1; e += 2) {
    int2 p0 = csr[e], p1 = csr[e + 1];
    float v0 = x[p0.x * 9 + f] + fmaf(__int_as_float(p0.y), we, be);
    float v1 = x[p1.x * 9 + f] + fmaf(__int_as_float(p1.y), we, be);
    acc += fmaxf(v0, 0.f) + fmaxf(v1, 0.f);
  }
  if (e < o1) {
    int2 p = csr[e];
    acc += fmaxf(x[p.x * 9 + f] + fmaf(__int_as_float(p.y), we, be), 0.f);
  }
  u1[node * 9 + f] = x[node * 9 + f] + acc;
}

// ---------------- Layer-2 aggregation: one wave per node ----------------
__global__ void __launch_bounds__(256) k_agg2(
    const float* __restrict__ h1, const int2* __restrict__ csr,
    const int* __restrict__ offs, const float* __restrict__ We2,
    const float* __restrict__ be2, float* __restrict__ u2, int N) {
  int gt = blockIdx.x * TPB + threadIdx.x;
  int node = gt >> 6, f = gt & 63;
  if (node >= N) return;
  int o0 = offs[node], o1 = offs[node + 1];
  float we = We2[f], be = be2[f];
  float acc = 0.f;
  int e = o0;
  for (; e + 3 < o1; e += 4) {
    int2 p0 = csr[e], p1 = csr[e + 1], p2 = csr[e + 2], p3 = csr[e + 3];
    float v0 = h1[p0.x * 64 + f] + fmaf(__int_as_float(p0.y), we, be);
    float v1 = h1[p1.x * 64 + f] + fmaf(__int_as_float(p1.y), we, be);
    float v2 = h1[p2.x * 64 + f] + fmaf(__int_as_float(p2.y), we, be);
    float v3 = h1[p3.x * 64 + f] + fmaf(__int_as_float(p3.y), we, be);
    acc += fmaxf(v0, 0.f) + fmaxf(v1, 0.f) + fmaxf(v2, 0.f) + fmaxf(v3, 0.f);
  }
  for (; e < o1; ++e) {
    int2 p = csr[e];
    acc += fmaxf(h1[p.x * 64 + f] + fmaf(__int_as_float(p.y), we, be), 0.f);
  }
  u2[node * 64 + f] = h1[node * 64 + f] + acc;
}

// ---------------- 2-layer MLP: relu(relu(u@Wa+ba)@Wb+bb), tile 64 nodes ----------------
template <int KIN>
__global__ void __launch_bounds__(256) k_mlp(
    const float* __restrict__ uin, const float* __restrict__ Wa,
    const float* __restrict__ ba, const float* __restrict__ Wb,
    const float* __restrict__ bb, float* __restrict__ hout, int N) {
  constexpr int US = (KIN == 64) ? 65 : KIN;
  __shared__ float ls_in[64 * US];
  __shared__ float ls_z[64 * 65];
  __shared__ float ls_w[64 * 64];
  __shared__ float ls_b[128];
  const int t = threadIdx.x;
  const int n0 = blockIdx.x * 64;

  for (int i = t; i < 64 * KIN; i += TPB) {
    int r = i / KIN, c = i % KIN;
    int g = n0 + r;
    ls_in[r * US + c] = (g < N) ? uin[g * KIN + c] : 0.f;
  }
  for (int i = t; i < KIN * 64; i += TPB) ls_w[i] = Wa[i];
  if (t < 64) { ls_b[t] = ba[t]; ls_b[64 + t] = bb[t]; }
  __syncthreads();

  const int of = (t & 15) * 4, nb = (t >> 4) * 4;
  float acc[4][4];
#pragma unroll
  for (int i = 0; i < 4; ++i)
#pragma unroll
    for (int j = 0; j < 4; ++j) acc[i][j] = 0.f;

  for (int k = 0; k < KIN; ++k) {
    float4 w = *(const float4*)&ls_w[k * 64 + of];
#pragma unroll
    for (int ni = 0; ni < 4; ++ni) {
      float uv = ls_in[(nb + ni) * US + k];
      acc[ni][0] += uv * w.x; acc[ni][1] += uv * w.y;
      acc[ni][2] += uv * w.z; acc[ni][3] += uv * w.w;
    }
  }
#pragma unroll
  for (int ni = 0; ni < 4; ++ni)
#pragma unroll
    for (int oi = 0; oi < 4; ++oi)
      ls_z[(nb + ni) * 65 + of + oi] = fmaxf(acc[ni][oi] + ls_b[of + oi], 0.f);
  __syncthreads();
  for (int i = t; i < 4096; i += TPB) ls_w[i] = Wb[i];
  __syncthreads();

#pragma unroll
  for (int i = 0; i < 4; ++i)
#pragma unroll
    for (int j = 0; j < 4; ++j) acc[i][j] = 0.f;
  for (int k = 0; k < 64; ++k) {
    float4 w = *(const float4*)&ls_w[k * 64 + of];
#pragma unroll
    for (int ni = 0; ni < 4; ++ni) {
      float zv = ls_z[(nb + ni) * 65 + k];
      acc[ni][0] += zv * w.x; acc[ni][1] += zv * w.y;
      acc[ni][2] += zv * w.z; acc[ni][3] += zv * w.w;
    }
  }
#pragma unroll
  for (int ni = 0; ni < 4; ++ni) {
    int n = n0 + nb + ni;
    if (n < N) {
      float4 o;
      o.x = fmaxf(acc[ni][0] + ls_b[64 + of + 0], 0.f);
      o.y = fmaxf(acc[ni][1] + ls_b[64 + of + 1], 0.f);
      o.z = fmaxf(acc[ni][2] + ls_b[64 + of + 2], 0.f);
      o.w = fmaxf(acc[ni][3] + ls_b[64 + of + 3], 0.f);
      *(float4*)&hout[n * 64 + of] = o;
    }
  }
}

// ---------------- Readout: sigmoid(relu(h2@Wr1+br1)@Wr2+br2) * (1-mask) ----------------
__global__ void __launch_bounds__(256) k_readout(
    const float* __restrict__ h2, const float* __restrict__ Wr1,
    const float* __restrict__ br1, const float* __restrict__ Wr2,
    const float* __restrict__ br2, const int* __restrict__ tmask,
    float* __restrict__ pi, int N) {
  __shared__ float ls_h[32 * 65];
  __shared__ float ls_w[64 * 32];
  __shared__ float ls_w2[32];
  __shared__ float ls_b1[32];
  int t = threadIdx.x;
  int n0 = blockIdx.x * 32;
  for (int i = t; i < 32 * 64; i += TPB) {
    int r = i >> 6, c = i & 63;
    int g = n0 + r;
    ls_h[r * 65 + c] = (g < N) ? h2[g * 64 + c] : 0.f;
  }
  for (int i = t; i < 2048; i += TPB) ls_w[i] = Wr1[i];
  if (t < 32) { ls_w2[t] = Wr2[t]; ls_b1[t] = br1[t]; }
  __syncthreads();
  int of = t & 31, q = t >> 5;
  float b2 = br2[0];
#pragma unroll
  for (int j = 0; j < 4; ++j) {
    int n = q * 4 + j;
    float a = 0.f;
    for (int k = 0; k < 64; ++k) a += ls_h[n * 65 + k] * ls_w[k * 32 + of];
    float r = fmaxf(a + ls_b1[of], 0.f) * ls_w2[of];
    for (int s = 16; s > 0; s >>= 1) r += __shfl_down(r, s, 32);
    if (of == 0) {
      int g = n0 + n;
      if (g < N) {
        float sg = 1.f / (1.f + expf(-(r + b2)));
        pi[g] = sg * (1.f - (float)tmask[g]);
      }
    }
  }
}

// ---------------- Group sums (batch is sorted) ----------------
__global__ void k_grpsum(const float* __restrict__ pi, const float* __restrict__ c_cost,
                         const int* __restrict__ batch, float* __restrict__ exp_tot, int N) {
  __shared__ float lsf[256];
  __shared__ int lsi[256];
  int t = threadIdx.x;
  int i = blockIdx.x * TPB + t;
  bool valid = i < N;
  int g = valid ? batch[i] : 0;
  float v = valid ? pi[i] * c_cost[i] : 0.f;
  lsi[t] = valid ? g : 0x7fffffff;
  __syncthreads();
  for (int s = 128; s > 0; s >>= 1) { if (t < s) lsi[t] = min(lsi[t], lsi[t + s]); __syncthreads(); }
  int gmin = lsi[0];
  __syncthreads();
  lsi[t] = valid ? g : -1;
  __syncthreads();
  for (int s = 128; s > 0; s >>= 1) { if (t < s) lsi[t] = max(lsi[t], lsi[t + s]); __syncthreads(); }
  int gmax = lsi[0];
  __syncthreads();
  for (int gg = gmin; gg <= gmax; ++gg) {
    lsf[t] = (valid && g == gg) ? v : 0.f;
    __syncthreads();
    for (int s = 128; s > 0; s >>= 1) { if (t < s) lsf[t] += lsf[t + s]; __syncthreads(); }
    if (t == 0) atomicAdd(&exp_tot[gg], lsf[0]);
    __syncthreads();
  }
}

__global__ void k_final(const float* __restrict__ pi, const int* __restrict__ batch,
                        const float* __restrict__ B_total, const float* __restrict__ exp_tot,
                        float* __restrict__ out, int N) {
  int i = blockIdx.x * TPB + threadIdx.x;
  if (i < N) {
    int g = batch[i];
    float ratio = fminf(B_total[g] / (exp_tot[g] + 1e-12f), 1.f);
    out[i] = pi[i] * ratio;
  }
}

extern "C" void kernel_launch(void* const* d_in, const int* in_sizes, int n_in,
                              void* d_out, int out_size, void* d_ws, size_t ws_size,
                              hipStream_t stream) {
  const float* x     = (const float*)d_in[0];
  const int*   ei    = (const int*)d_in[1];
  const float* eattr = (const float*)d_in[2];
  const int*   batch = (const int*)d_in[3];
  const float* Btot  = (const float*)d_in[4];
  const int*   tmask = (const int*)d_in[5];
  const float* ccost = (const float*)d_in[6];
  const float* We1 = (const float*)d_in[7],  *be1 = (const float*)d_in[8];
  const float* W1a = (const float*)d_in[9],  *b1a = (const float*)d_in[10];
  const float* W1b = (const float*)d_in[11], *b1b = (const float*)d_in[12];
  const float* We2 = (const float*)d_in[13], *be2 = (const float*)d_in[14];
  const float* W2a = (const float*)d_in[15], *b2a = (const float*)d_in[16];
  const float* W2b = (const float*)d_in[17], *b2b = (const float*)d_in[18];
  const float* Wr1 = (const float*)d_in[19], *br1 = (const float*)d_in[20];
  const float* Wr2 = (const float*)d_in[21], *br2 = (const float*)d_in[22];
  float* out = (float*)d_out;

  const int N = in_sizes[0] / 9;
  const int E = in_sizes[2];
  const int G = in_sizes[4];
  const int* src = ei;
  const int* dst = ei + E;

  // workspace carve-up (4-byte elements, 64-elem aligned blocks)
  size_t cur = 0;
  auto alloc = [&](size_t elems) { size_t r = cur; cur += elems; cur = (cur + 63) & ~(size_t)63; return r; };
  char* wsb = (char*)d_ws;
  size_t o_deg    = alloc(N);
  size_t o_cursor = alloc(N);
  size_t o_exp    = alloc(G);
  size_t zero_bytes = cur * 4;          // deg+cursor+exp_tot contiguous prefix
  size_t o_offs   = alloc(N + 1);
  size_t o_bsums  = alloc(128);
  size_t o_csr    = alloc(2 * (size_t)E);  // int2
  size_t o_u1     = alloc((size_t)N * 9);
  size_t o_h1     = alloc((size_t)N * 64);
  size_t o_u2     = alloc((size_t)N * 64); // also h2 (overwritten in-place by k_mlp<64>)
  size_t o_pi     = alloc(N);
  (void)ws_size;

  int*   deg    = (int*)wsb + o_deg;
  int*   cursor = (int*)wsb + o_cursor;
  float* exp_t  = (float*)wsb + o_exp;
  int*   offs   = (int*)wsb + o_offs;
  int*   bsums  = (int*)wsb + o_bsums;
  int2*  csr    = (int2*)((int*)wsb + o_csr);
  float* u1     = (float*)wsb + o_u1;
  float* h1     = (float*)wsb + o_h1;
  float* u2     = (float*)wsb + o_u2;
  float* pi     = (float*)wsb + o_pi;

  hipMemsetAsync(d_ws, 0, zero_bytes, stream);

  const int gE = (E + TPB - 1) / TPB;
  const int nb = (N + 1023) / 1024;

  k_hist<<<gE, TPB, 0, stream>>>(dst, deg, E);
  k_scan_block<<<nb, TPB, 0, stream>>>(deg, offs, bsums, N);
  k_scan_mid<<<1, 128, 0, stream>>>(bsums, nb);
  k_scan_add<<<nb, TPB, 0, stream>>>(offs, bsums, N, E);
  k_fill<<<gE, TPB, 0, stream>>>(src, dst, eattr, offs, cursor, csr, E);

  k_agg1<<<((size_t)N * 16 + TPB - 1) / TPB, TPB, 0, stream>>>(x, csr, offs, We1, be1, u1, N);
  k_mlp<9><<<(N + 63) / 64, TPB, 0, stream>>>(u1, W1a, b1a, W1b, b1b, h1, N);

  k_agg2<<<((size_t)N * 64 + TPB - 1) / TPB, TPB, 0, stream>>>(h1, csr, offs, We2, be2, u2, N);
  k_mlp<64><<<(N + 63) / 64, TPB, 0, stream>>>(u2, W2a, b2a, W2b, b2b, u2, N);

  k_readout<<<(N + 31) / 32, TPB, 0, stream>>>(u2, Wr1, br1, Wr2, br2, tmask, pi, N);
  k_grpsum<<<(N + TPB - 1) / TPB, TPB, 0, stream>>>(pi, ccost, batch, exp_t, N);
  k_final<<<(N + TPB - 1) / TPB, TPB, 0, stream>>>(pi, batch, Btot, exp_t, out, N);
}